// Round 1
// baseline (2512.992 us; speedup 1.0000x reference)
//
#include <hip/hip_runtime.h>
#include <hip/hip_bf16.h>

#define N_NODES 200000
#define N_EDGES 2500000
#define HID 32
#define BN_EPS 1e-5f

__device__ __forceinline__ void atomAdd(float* p, float v) {
    unsafeAtomicAdd(p, v);   // native global_atomic_add_f32 on gfx950
}

// K1: deg starts at 1.0 (self-loop in A+I); zero the stats scratch.
__global__ void k_init(float* __restrict__ norm, float* __restrict__ stats) {
    int i = blockIdx.x * blockDim.x + threadIdx.x;
    if (i < N_NODES) norm[i] = 1.0f;
    if (i < 256) stats[i] = 0.0f;
}

// K2: deg[dst] += 1 per edge
__global__ void k_deg(const int* __restrict__ ei, float* __restrict__ norm) {
    int e = blockIdx.x * blockDim.x + threadIdx.x;
    if (e < N_EDGES) atomAdd(&norm[ei[N_EDGES + e]], 1.0f);
}

// K3: norm = rsqrt(deg) in place; s = x * norm^2 (layer-1 self-loop term)
__global__ void k_norm(const float* __restrict__ x, float* __restrict__ norm,
                       float* __restrict__ s) {
    int i = blockIdx.x * blockDim.x + threadIdx.x;
    if (i < N_NODES) {
        float nm = rsqrtf(norm[i]);
        norm[i] = nm;
        s[i] = x[i] * nm * nm;
    }
}

// K4: coef[e] = norm[src]*norm[dst]; layer-1 scalar scatter s[dst] += coef*x[src]
__global__ void k_edge1(const int* __restrict__ ei, const float* __restrict__ x,
                        const float* __restrict__ norm, float* __restrict__ coef,
                        float* __restrict__ s) {
    int e = blockIdx.x * blockDim.x + threadIdx.x;
    if (e < N_EDGES) {
        int sN = ei[e], dN = ei[N_EDGES + e];
        float c = norm[sN] * norm[dN];
        coef[e] = c;
        atomAdd(&s[dN], c * x[sN]);
    }
}

// K5: scalar sum / sumsq of s
__global__ void k_stats_s(const float* __restrict__ s, float* __restrict__ stats) {
    __shared__ float ls[256], lq[256];
    float a = 0.f, q = 0.f;
    for (int i = blockIdx.x * blockDim.x + threadIdx.x; i < N_NODES;
         i += gridDim.x * blockDim.x) {
        float v = s[i];
        a += v; q += v * v;
    }
    ls[threadIdx.x] = a; lq[threadIdx.x] = q;
    __syncthreads();
    for (int off = 128; off; off >>= 1) {
        if (threadIdx.x < (unsigned)off) {
            ls[threadIdx.x] += ls[threadIdx.x + off];
            lq[threadIdx.x] += lq[threadIdx.x + off];
        }
        __syncthreads();
    }
    if (threadIdx.x == 0) { atomAdd(&stats[0], ls[0]); atomAdd(&stats[1], lq[0]); }
}

// K6: fused layer-1 BN+ReLU (rank-1 form) + y1@W2 + self-loop init for layer 2.
// Block = 256 threads = 8 nodes x 32 channels.
__global__ void __launch_bounds__(256)
k_fusedA(const float* __restrict__ s, const float* __restrict__ norm,
         const float* __restrict__ stats, const float* __restrict__ W1,
         const float* __restrict__ g1, const float* __restrict__ be1,
         const float* __restrict__ W2, float* __restrict__ A, float* __restrict__ B) {
    __shared__ float w2[32 * 32];
    __shared__ float aj[32], sj[32];
    __shared__ float y[8][33];
    int tid = threadIdx.x;
    for (int i = tid; i < 1024; i += 256) w2[i] = W2[i];
    if (tid < 32) {
        float m   = stats[0] * (1.0f / N_NODES);
        float var = stats[1] * (1.0f / N_NODES) - m * m;
        float w = W1[tid];
        // pre-BN = s*w (+b, cancels); mean_j = m*w; var_j = var*w^2
        float a = g1[tid] * w * rsqrtf(var * w * w + BN_EPS);
        aj[tid] = a;
        sj[tid] = be1[tid] - m * a;
    }
    int nl = tid >> 5, j = tid & 31;
    int n = blockIdx.x * 8 + nl;
    __syncthreads();
    float sv = (n < N_NODES) ? s[n] : 0.f;
    y[nl][j] = fmaxf(aj[j] * sv + sj[j], 0.f);
    __syncthreads();
    if (n < N_NODES) {
        float acc = 0.f;
#pragma unroll
        for (int k = 0; k < 32; k++) acc += y[nl][k] * w2[k * 32 + j];
        A[n * 32 + j] = acc;
        float nm = norm[n];
        B[n * 32 + j] = acc * nm * nm;   // self-loop init of next agg
    }
}

// K7: edge message+scatter for H=32. 8 threads per edge, float4 each.
__global__ void __launch_bounds__(256)
k_edge32(const int* __restrict__ ei, const float* __restrict__ coef,
         const float* __restrict__ h, float* __restrict__ agg) {
    int t = blockIdx.x * blockDim.x + threadIdx.x;   // < E*8 = 20M
    if (t >= N_EDGES * 8) return;
    int e = t >> 3;
    int c = (t & 7) * 4;
    int sN = ei[e], dN = ei[N_EDGES + e];
    float cf = coef[e];
    const float4 v = *(const float4*)(h + sN * 32 + c);
    float* p = agg + dN * 32 + c;
    atomAdd(p + 0, v.x * cf);
    atomAdd(p + 1, v.y * cf);
    atomAdd(p + 2, v.z * cf);
    atomAdd(p + 3, v.w * cf);
}

// K8: per-channel sum/sumsq over the node dimension.
__global__ void k_stats32(const float* __restrict__ agg, float* __restrict__ sum,
                          float* __restrict__ sumsq) {
    int j = threadIdx.x & 31;
    int rl = threadIdx.x >> 5;   // 0..7
    float a = 0.f, q = 0.f;
    for (int n = blockIdx.x * 8 + rl; n < N_NODES; n += gridDim.x * 8) {
        float v = agg[n * 32 + j];
        a += v; q += v * v;
    }
    __shared__ float ls[8][32], lq[8][32];
    ls[rl][j] = a; lq[rl][j] = q;
    __syncthreads();
    for (int off = 4; off; off >>= 1) {
        if (rl < off) { ls[rl][j] += ls[rl + off][j]; lq[rl][j] += lq[rl + off][j]; }
        __syncthreads();
    }
    if (rl == 0) { atomAdd(&sum[j], ls[0][j]); atomAdd(&sumsq[j], lq[0][j]); }
}

// K9: fused BN+ReLU + y@W + self-loop init. aggIn may alias aggOut (each
// element is read then written by the same thread).
__global__ void __launch_bounds__(256)
k_fusedB(const float* __restrict__ norm, const float* __restrict__ sum,
         const float* __restrict__ sumsq, const float* __restrict__ g,
         const float* __restrict__ be, const float* __restrict__ W,
         const float* aggIn, float* __restrict__ hOut, float* aggOut) {
    __shared__ float wl[1024];
    __shared__ float sc[32], sh[32];
    __shared__ float y[8][33];
    int tid = threadIdx.x;
    for (int i = tid; i < 1024; i += 256) wl[i] = W[i];
    if (tid < 32) {
        float m   = sum[tid] * (1.0f / N_NODES);
        float var = sumsq[tid] * (1.0f / N_NODES) - m * m;
        float scj = g[tid] * rsqrtf(var + BN_EPS);
        sc[tid] = scj;
        sh[tid] = be[tid] - m * scj;
    }
    int nl = tid >> 5, j = tid & 31;
    int n = blockIdx.x * 8 + nl;
    __syncthreads();
    float yv = 0.f;
    if (n < N_NODES) yv = fmaxf(sc[j] * aggIn[n * 32 + j] + sh[j], 0.f);
    y[nl][j] = yv;
    __syncthreads();
    if (n < N_NODES) {
        float acc = 0.f;
#pragma unroll
        for (int k = 0; k < 32; k++) acc += y[nl][k] * wl[k * 32 + j];
        hOut[n * 32 + j] = acc;
        float nm = norm[n];
        aggOut[n * 32 + j] = acc * nm * nm;
    }
}

// K10: final BN+ReLU + dot with fcW + fcb.
__global__ void __launch_bounds__(256)
k_final(const float* __restrict__ aggIn, const float* __restrict__ sum,
        const float* __restrict__ sumsq, const float* __restrict__ g,
        const float* __restrict__ be, const float* __restrict__ fcW,
        const float* __restrict__ fcb, float* __restrict__ out) {
    __shared__ float sc[32], sh[32], fw[32];
    int tid = threadIdx.x;
    if (tid < 32) {
        float m   = sum[tid] * (1.0f / N_NODES);
        float var = sumsq[tid] * (1.0f / N_NODES) - m * m;
        float scj = g[tid] * rsqrtf(var + BN_EPS);
        sc[tid] = scj;
        sh[tid] = be[tid] - m * scj;
        fw[tid] = fcW[tid];
    }
    __syncthreads();
    int nl = tid >> 5, j = tid & 31;
    int n = blockIdx.x * 8 + nl;
    float v = 0.f;
    if (n < N_NODES) v = fmaxf(sc[j] * aggIn[n * 32 + j] + sh[j], 0.f) * fw[j];
    for (int off = 16; off; off >>= 1) v += __shfl_down(v, off, 32);
    if (j == 0 && n < N_NODES) out[n] = v + fcb[0];
}

extern "C" void kernel_launch(void* const* d_in, const int* in_sizes, int n_in,
                              void* d_out, int out_size, void* d_ws, size_t ws_size,
                              hipStream_t stream) {
    const float* x   = (const float*)d_in[0];
    const int*   ei  = (const int*)d_in[1];
    // d_in[2] edge_attr: unused by the reference
    const float* W1  = (const float*)d_in[3];
    // b1/b2/b3 cancel under training-mode BN
    const float* g1  = (const float*)d_in[5];
    const float* be1 = (const float*)d_in[6];
    const float* W2  = (const float*)d_in[7];
    const float* g2  = (const float*)d_in[9];
    const float* be2 = (const float*)d_in[10];
    const float* W3  = (const float*)d_in[11];
    const float* g3  = (const float*)d_in[13];
    const float* be3 = (const float*)d_in[14];
    const float* fcW = (const float*)d_in[15];
    const float* fcb = (const float*)d_in[16];
    float* out = (float*)d_out;

    float* ws    = (float*)d_ws;
    float* norm  = ws;                    // [N] (deg -> norm in place)
    float* s     = ws + N_NODES;          // [N]
    float* stats = ws + 2 * N_NODES;      // [256]: [0..1]=s; [8..39]/[40..71]=L2; [72..103]/[104..135]=L3
    float* coef  = stats + 256;           // [E]
    float* A     = coef + N_EDGES;        // [N*32] h buffer
    float* B     = A + N_NODES * 32;      // [N*32] agg buffer

    const int nbN = (N_NODES + 255) / 256;
    const int nbE = (N_EDGES + 255) / 256;
    const int nbE8 = (N_EDGES * 8 + 255) / 256;
    const int nbNode8 = (N_NODES + 7) / 8;

    k_init <<<nbN, 256, 0, stream>>>(norm, stats);
    k_deg  <<<nbE, 256, 0, stream>>>(ei, norm);
    k_norm <<<nbN, 256, 0, stream>>>(x, norm, s);
    k_edge1<<<nbE, 256, 0, stream>>>(ei, x, norm, coef, s);
    k_stats_s<<<256, 256, 0, stream>>>(s, stats);
    k_fusedA<<<nbNode8, 256, 0, stream>>>(s, norm, stats, W1, g1, be1, W2, A, B);
    k_edge32<<<nbE8, 256, 0, stream>>>(ei, coef, A, B);
    k_stats32<<<512, 256, 0, stream>>>(B, stats + 8, stats + 40);
    k_fusedB<<<nbNode8, 256, 0, stream>>>(norm, stats + 8, stats + 40, g2, be2, W3, B, A, B);
    k_edge32<<<nbE8, 256, 0, stream>>>(ei, coef, A, B);
    k_stats32<<<512, 256, 0, stream>>>(B, stats + 72, stats + 104);
    k_final<<<nbNode8, 256, 0, stream>>>(B, stats + 72, stats + 104, g3, be3, fcW, fcb, out);
}

// Round 2
// 671.913 us; speedup vs baseline: 3.7401x; 3.7401x over previous
//
#include <hip/hip_runtime.h>
#include <hip/hip_bf16.h>

#define N_NODES 200000
#define N_EDGES 2500000
#define HID 32
#define BN_EPS 1e-5f
#define SCAN_CHUNK 1024
#define NSCAN_BLOCKS ((N_NODES + SCAN_CHUNK - 1) / SCAN_CHUNK)   // 196 (<=256)

__device__ __forceinline__ void atomAddF(float* p, float v) {
    unsafeAtomicAdd(p, v);   // native global_atomic_add_f32 on gfx950
}

// K1: zero the per-node in-degree counters and the stats scratch.
__global__ void k_init(int* __restrict__ cnt, float* __restrict__ stats) {
    int i = blockIdx.x * blockDim.x + threadIdx.x;
    if (i < N_NODES) cnt[i] = 0;
    if (i < 256) stats[i] = 0.0f;
}

// K2: in-degree histogram (int atomics — cheap vs f32 scatter atomics).
__global__ void k_hist(const int* __restrict__ ei, int* __restrict__ cnt) {
    int e = blockIdx.x * blockDim.x + threadIdx.x;
    if (e < N_EDGES) atomicAdd(&cnt[ei[N_EDGES + e]], 1);
}

// K3a: per-chunk sums for the hierarchical exclusive scan.
__global__ void k_scan1(const int* __restrict__ cnt, int* __restrict__ bsum) {
    __shared__ int sh[256];
    int base = blockIdx.x * SCAN_CHUNK;
    int t = threadIdx.x;
    int s = 0;
#pragma unroll
    for (int k = 0; k < 4; k++) {
        int idx = base + t * 4 + k;
        if (idx < N_NODES) s += cnt[idx];
    }
    sh[t] = s; __syncthreads();
    for (int off = 128; off; off >>= 1) {
        if (t < off) sh[t] += sh[t + off];
        __syncthreads();
    }
    if (t == 0) bsum[blockIdx.x] = sh[0];
}

// K3b: exclusive scan of the 196 chunk sums (one block).
__global__ void k_scan2(int* __restrict__ bsum) {
    __shared__ int sh[256];
    int t = threadIdx.x;
    int v = (t < NSCAN_BLOCKS) ? bsum[t] : 0;
    sh[t] = v; __syncthreads();
    for (int off = 1; off < 256; off <<= 1) {
        int add = (t >= off) ? sh[t - off] : 0;
        __syncthreads();
        sh[t] += add;
        __syncthreads();
    }
    if (t < NSCAN_BLOCKS) bsum[t] = sh[t] - v;   // exclusive
}

// K3c: chunk-local scan + chunk offset -> rowptr (exclusive). Also:
// cursor init (reuses cnt storage), norm = rsqrt(deg+1), xp = x*norm.
__global__ void k_scan3(int* __restrict__ cnt /* in: counts, out: cursor */,
                        const int* __restrict__ bsum, int* __restrict__ rowptr,
                        const float* __restrict__ x, float* __restrict__ norm,
                        float* __restrict__ xp) {
    __shared__ int sh[256];
    int base = blockIdx.x * SCAN_CHUNK;
    int t = threadIdx.x;
    int c[4]; int local = 0;
#pragma unroll
    for (int k = 0; k < 4; k++) {
        int idx = base + t * 4 + k;
        c[k] = (idx < N_NODES) ? cnt[idx] : 0;
        local += c[k];
    }
    sh[t] = local; __syncthreads();
    for (int off = 1; off < 256; off <<= 1) {
        int add = (t >= off) ? sh[t - off] : 0;
        __syncthreads();
        sh[t] += add;
        __syncthreads();
    }
    int excl = sh[t] - local + bsum[blockIdx.x];
#pragma unroll
    for (int k = 0; k < 4; k++) {
        int idx = base + t * 4 + k;
        if (idx < N_NODES) {
            rowptr[idx] = excl;
            cnt[idx] = excl;                       // cursor init
            float nm = rsqrtf((float)c[k] + 1.0f);
            norm[idx] = nm;
            xp[idx] = x[idx] * nm;
            excl += c[k];
        }
    }
    if (blockIdx.x == 0 && t == 0) rowptr[N_NODES] = N_EDGES;
}

// K4: place each edge's src into CSR slot (int atomic on cursor).
__global__ void k_build(const int* __restrict__ ei, int* __restrict__ cursor,
                        int* __restrict__ csrc) {
    int e = blockIdx.x * blockDim.x + threadIdx.x;
    if (e < N_EDGES) {
        int d = ei[N_EDGES + e];
        int pos = atomicAdd(&cursor[d], 1);
        csrc[pos] = ei[e];
    }
}

// K5: layer-1 scalar aggregation via gather: s[n] = norm[n]*(xp[n] + sum xp[src]).
__global__ void k_gather1(const int* __restrict__ rowptr, const int* __restrict__ csrc,
                          const float* __restrict__ xp, const float* __restrict__ norm,
                          float* __restrict__ s) {
    int n = blockIdx.x * blockDim.x + threadIdx.x;
    if (n >= N_NODES) return;
    int beg = rowptr[n], end = rowptr[n + 1];
    float acc = xp[n];
    for (int i = beg; i < end; i++) acc += xp[csrc[i]];
    s[n] = norm[n] * acc;
}

// K6: scalar sum / sumsq of s.
__global__ void k_stats_s(const float* __restrict__ s, float* __restrict__ stats) {
    __shared__ float ls[256], lq[256];
    float a = 0.f, q = 0.f;
    for (int i = blockIdx.x * blockDim.x + threadIdx.x; i < N_NODES;
         i += gridDim.x * blockDim.x) {
        float v = s[i];
        a += v; q += v * v;
    }
    ls[threadIdx.x] = a; lq[threadIdx.x] = q;
    __syncthreads();
    for (int off = 128; off; off >>= 1) {
        if (threadIdx.x < (unsigned)off) {
            ls[threadIdx.x] += ls[threadIdx.x + off];
            lq[threadIdx.x] += lq[threadIdx.x + off];
        }
        __syncthreads();
    }
    if (threadIdx.x == 0) { atomAddF(&stats[0], ls[0]); atomAddF(&stats[1], lq[0]); }
}

// K7: fused layer-1 BN+ReLU (rank-1 form) + y1@W2, pre-scaled by norm[n].
// Block = 256 threads = 8 nodes x 32 channels.
__global__ void __launch_bounds__(256)
k_fusedA(const float* __restrict__ s, const float* __restrict__ norm,
         const float* __restrict__ stats, const float* __restrict__ W1,
         const float* __restrict__ g1, const float* __restrict__ be1,
         const float* __restrict__ W2, float* __restrict__ A) {
    __shared__ float w2[32 * 32];
    __shared__ float aj[32], sj[32];
    __shared__ float y[8][33];
    int tid = threadIdx.x;
    for (int i = tid; i < 1024; i += 256) w2[i] = W2[i];
    if (tid < 32) {
        float m   = stats[0] * (1.0f / N_NODES);
        float var = stats[1] * (1.0f / N_NODES) - m * m;
        float w = W1[tid];
        float a = g1[tid] * w * rsqrtf(var * w * w + BN_EPS);
        aj[tid] = a;
        sj[tid] = be1[tid] - m * a;
    }
    int nl = tid >> 5, j = tid & 31;
    int n = blockIdx.x * 8 + nl;
    __syncthreads();
    float sv = (n < N_NODES) ? s[n] : 0.f;
    y[nl][j] = fmaxf(aj[j] * sv + sj[j], 0.f);
    __syncthreads();
    if (n < N_NODES) {
        float acc = 0.f;
#pragma unroll
        for (int k = 0; k < 32; k++) acc += y[nl][k] * w2[k * 32 + j];
        A[n * 32 + j] = acc * norm[n];     // pre-scale by source norm
    }
}

// K8: CSR gather-aggregate for H=32. 8 threads/node, float4 each:
// B[n] = norm[n] * (A[n] + sum_{in-edges} A[src]).
__global__ void __launch_bounds__(256)
k_gather32(const int* __restrict__ rowptr, const int* __restrict__ csrc,
           const float* __restrict__ A, const float* __restrict__ norm,
           float* __restrict__ B) {
    int tid = threadIdx.x;
    int n = blockIdx.x * 32 + (tid >> 3);
    if (n >= N_NODES) return;
    int c = (tid & 7) * 4;
    int beg = rowptr[n], end = rowptr[n + 1];
    float4 acc = *(const float4*)(A + n * 32 + c);    // self-loop term
    int i = beg;
    for (; i + 1 < end; i += 2) {
        int s0 = csrc[i], s1 = csrc[i + 1];
        float4 v0 = *(const float4*)(A + s0 * 32 + c);
        float4 v1 = *(const float4*)(A + s1 * 32 + c);
        acc.x += v0.x + v1.x; acc.y += v0.y + v1.y;
        acc.z += v0.z + v1.z; acc.w += v0.w + v1.w;
    }
    if (i < end) {
        float4 v = *(const float4*)(A + csrc[i] * 32 + c);
        acc.x += v.x; acc.y += v.y; acc.z += v.z; acc.w += v.w;
    }
    float nm = norm[n];
    float4 o; o.x = acc.x * nm; o.y = acc.y * nm; o.z = acc.z * nm; o.w = acc.w * nm;
    *(float4*)(B + n * 32 + c) = o;
}

// K9: per-channel sum/sumsq over the node dimension.
__global__ void k_stats32(const float* __restrict__ agg, float* __restrict__ sum,
                          float* __restrict__ sumsq) {
    int j = threadIdx.x & 31;
    int rl = threadIdx.x >> 5;   // 0..7
    float a = 0.f, q = 0.f;
    for (int n = blockIdx.x * 8 + rl; n < N_NODES; n += gridDim.x * 8) {
        float v = agg[n * 32 + j];
        a += v; q += v * v;
    }
    __shared__ float ls[8][32], lq[8][32];
    ls[rl][j] = a; lq[rl][j] = q;
    __syncthreads();
    for (int off = 4; off; off >>= 1) {
        if (rl < off) { ls[rl][j] += ls[rl + off][j]; lq[rl][j] += lq[rl + off][j]; }
        __syncthreads();
    }
    if (rl == 0) { atomAddF(&sum[j], ls[0][j]); atomAddF(&sumsq[j], lq[0][j]); }
}

// K10: fused BN+ReLU + y@W, pre-scaled by norm[n]. Reads B, writes A.
__global__ void __launch_bounds__(256)
k_fusedB(const float* __restrict__ norm, const float* __restrict__ sum,
         const float* __restrict__ sumsq, const float* __restrict__ g,
         const float* __restrict__ be, const float* __restrict__ W,
         const float* __restrict__ aggIn, float* __restrict__ hOut) {
    __shared__ float wl[1024];
    __shared__ float sc[32], sh[32];
    __shared__ float y[8][33];
    int tid = threadIdx.x;
    for (int i = tid; i < 1024; i += 256) wl[i] = W[i];
    if (tid < 32) {
        float m   = sum[tid] * (1.0f / N_NODES);
        float var = sumsq[tid] * (1.0f / N_NODES) - m * m;
        float scj = g[tid] * rsqrtf(var + BN_EPS);
        sc[tid] = scj;
        sh[tid] = be[tid] - m * scj;
    }
    int nl = tid >> 5, j = tid & 31;
    int n = blockIdx.x * 8 + nl;
    __syncthreads();
    float yv = 0.f;
    if (n < N_NODES) yv = fmaxf(sc[j] * aggIn[n * 32 + j] + sh[j], 0.f);
    y[nl][j] = yv;
    __syncthreads();
    if (n < N_NODES) {
        float acc = 0.f;
#pragma unroll
        for (int k = 0; k < 32; k++) acc += y[nl][k] * wl[k * 32 + j];
        hOut[n * 32 + j] = acc * norm[n];
    }
}

// K11: final BN+ReLU + dot with fcW + fcb.
__global__ void __launch_bounds__(256)
k_final(const float* __restrict__ aggIn, const float* __restrict__ sum,
        const float* __restrict__ sumsq, const float* __restrict__ g,
        const float* __restrict__ be, const float* __restrict__ fcW,
        const float* __restrict__ fcb, float* __restrict__ out) {
    __shared__ float sc[32], sh[32], fw[32];
    int tid = threadIdx.x;
    if (tid < 32) {
        float m   = sum[tid] * (1.0f / N_NODES);
        float var = sumsq[tid] * (1.0f / N_NODES) - m * m;
        float scj = g[tid] * rsqrtf(var + BN_EPS);
        sc[tid] = scj;
        sh[tid] = be[tid] - m * scj;
        fw[tid] = fcW[tid];
    }
    __syncthreads();
    int nl = tid >> 5, j = tid & 31;
    int n = blockIdx.x * 8 + nl;
    float v = 0.f;
    if (n < N_NODES) v = fmaxf(sc[j] * aggIn[n * 32 + j] + sh[j], 0.f) * fw[j];
    for (int off = 16; off; off >>= 1) v += __shfl_down(v, off, 32);
    if (j == 0 && n < N_NODES) out[n] = v + fcb[0];
}

extern "C" void kernel_launch(void* const* d_in, const int* in_sizes, int n_in,
                              void* d_out, int out_size, void* d_ws, size_t ws_size,
                              hipStream_t stream) {
    const float* x   = (const float*)d_in[0];
    const int*   ei  = (const int*)d_in[1];
    // d_in[2] edge_attr: unused by the reference
    const float* W1  = (const float*)d_in[3];
    // b1/b2/b3 cancel under training-mode BN
    const float* g1  = (const float*)d_in[5];
    const float* be1 = (const float*)d_in[6];
    const float* W2  = (const float*)d_in[7];
    const float* g2  = (const float*)d_in[9];
    const float* be2 = (const float*)d_in[10];
    const float* W3  = (const float*)d_in[11];
    const float* g3  = (const float*)d_in[13];
    const float* be3 = (const float*)d_in[14];
    const float* fcW = (const float*)d_in[15];
    const float* fcb = (const float*)d_in[16];
    float* out = (float*)d_out;

    // Workspace layout (A/B first for 16B alignment of float4 rows)
    float* A      = (float*)d_ws;                 // [N*32]
    float* B      = A + N_NODES * 32;             // [N*32]
    int*   cnt    = (int*)(B + N_NODES * 32);     // [N]  counts -> cursor
    int*   rowptr = cnt + N_NODES;                // [N+1]
    int*   bsum   = rowptr + N_NODES + 1;         // [256]
    int*   csrc   = bsum + 256;                   // [E]
    float* norm   = (float*)(csrc + N_EDGES);     // [N]
    float* xp     = norm + N_NODES;               // [N]
    float* s      = xp + N_NODES;                 // [N]
    float* stats  = s + N_NODES;                  // [256]

    const int nbN = (N_NODES + 255) / 256;
    const int nbE = (N_EDGES + 255) / 256;
    const int nbNode8  = (N_NODES + 7) / 8;       // fused kernels: 8 nodes/block
    const int nbNode32 = (N_NODES + 31) / 32;     // gather32: 32 nodes/block

    k_init <<<nbN, 256, 0, stream>>>(cnt, stats);
    k_hist <<<nbE, 256, 0, stream>>>(ei, cnt);
    k_scan1<<<NSCAN_BLOCKS, 256, 0, stream>>>(cnt, bsum);
    k_scan2<<<1, 256, 0, stream>>>(bsum);
    k_scan3<<<NSCAN_BLOCKS, 256, 0, stream>>>(cnt, bsum, rowptr, x, norm, xp);
    k_build<<<nbE, 256, 0, stream>>>(ei, cnt, csrc);
    k_gather1<<<nbN, 256, 0, stream>>>(rowptr, csrc, xp, norm, s);
    k_stats_s<<<256, 256, 0, stream>>>(s, stats);
    k_fusedA<<<nbNode8, 256, 0, stream>>>(s, norm, stats, W1, g1, be1, W2, A);
    k_gather32<<<nbNode32, 256, 0, stream>>>(rowptr, csrc, A, norm, B);
    k_stats32<<<512, 256, 0, stream>>>(B, stats + 8, stats + 40);
    k_fusedB<<<nbNode8, 256, 0, stream>>>(norm, stats + 8, stats + 40, g2, be2, W3, B, A);
    k_gather32<<<nbNode32, 256, 0, stream>>>(rowptr, csrc, A, norm, B);
    k_stats32<<<512, 256, 0, stream>>>(B, stats + 72, stats + 104);
    k_final<<<nbNode8, 256, 0, stream>>>(B, stats + 72, stats + 104, g3, be3, fcW, fcb, out);
}

// Round 3
// 463.621 us; speedup vs baseline: 5.4204x; 1.4493x over previous
//
#include <hip/hip_runtime.h>
#include <hip/hip_bf16.h>

#define N_NODES 200000
#define N_EDGES 2500000
#define HID 32
#define BN_EPS 1e-5f
#define SCAN_CHUNK 1024
#define NSCAN_BLOCKS ((N_NODES + SCAN_CHUNK - 1) / SCAN_CHUNK)   // 196 (<=256)

#define BKT_SHIFT 9                      // 512 nodes per bucket
#define B_BKT ((N_NODES + 511) / 512)    // 391 buckets
#define PAD 16                           // one counter per 64B line
#define EDGES_PER_BLK 8192
#define NB_SCAT ((N_EDGES + EDGES_PER_BLK - 1) / EDGES_PER_BLK)  // 306

__device__ __forceinline__ void atomAddF(float* p, float v) {
    unsafeAtomicAdd(p, v);   // native global_atomic_add_f32 on gfx950
}

// K0: zero bucket counters + stats scratch.
__global__ void k_init(int* __restrict__ bcnt16, float* __restrict__ stats) {
    int i = blockIdx.x * blockDim.x + threadIdx.x;
    if (i < B_BKT * PAD) bcnt16[i] = 0;
    if (i < 256) stats[i] = 0.0f;
}

// S1: bucket histogram via per-block LDS privatization.
__global__ void __launch_bounds__(256)
k_bhist(const int* __restrict__ ei, int* __restrict__ bcnt16) {
    __shared__ int lh[B_BKT];
    for (int i = threadIdx.x; i < B_BKT; i += 256) lh[i] = 0;
    __syncthreads();
    int base = blockIdx.x * EDGES_PER_BLK;
#pragma unroll 4
    for (int k = 0; k < 32; k++) {
        int e = base + k * 256 + threadIdx.x;
        if (e < N_EDGES) atomicAdd(&lh[ei[N_EDGES + e] >> BKT_SHIFT], 1);
    }
    __syncthreads();
    for (int i = threadIdx.x; i < B_BKT; i += 256)
        if (lh[i]) atomicAdd(&bcnt16[i * PAD], lh[i]);
}

// S2: exclusive scan of 391 bucket counts (one block); init padded cursors.
__global__ void k_bscan(const int* __restrict__ bcnt16, int* __restrict__ boff,
                        int* __restrict__ bcur16) {
    __shared__ int sh[512];
    int t = threadIdx.x;
    int v0 = (t < B_BKT) ? bcnt16[t * PAD] : 0;
    int v1 = (t + 256 < B_BKT) ? bcnt16[(t + 256) * PAD] : 0;
    sh[t] = v0; sh[t + 256] = v1;
    __syncthreads();
    for (int off = 1; off < 512; off <<= 1) {
        int a = (t >= off) ? sh[t - off] : 0;
        int b = (t + 256 >= off) ? sh[t + 256 - off] : 0;
        __syncthreads();
        sh[t] += a; sh[t + 256] += b;
        __syncthreads();
    }
    if (t < B_BKT) { boff[t] = sh[t] - v0; bcur16[t * PAD] = sh[t] - v0; }
    if (t + 256 < B_BKT) { boff[t + 256] = sh[t + 256] - v1; bcur16[(t + 256) * PAD] = sh[t + 256] - v1; }
    if (t == 0) boff[B_BKT] = N_EDGES;
}

// S3: scatter edges into bucket-grouped ebuf. Per-block bulk reservation keeps
// each block's writes contiguous per bucket (single-XCD, L2-dense).
__global__ void __launch_bounds__(256)
k_scatterB(const int* __restrict__ ei, int* __restrict__ bcur16,
           int2* __restrict__ ebuf) {
    __shared__ int lh[B_BKT], lbase[B_BKT], lc[B_BKT];
    for (int i = threadIdx.x; i < B_BKT; i += 256) { lh[i] = 0; lc[i] = 0; }
    __syncthreads();
    int base = blockIdx.x * EDGES_PER_BLK;
#pragma unroll 4
    for (int k = 0; k < 32; k++) {
        int e = base + k * 256 + threadIdx.x;
        if (e < N_EDGES) atomicAdd(&lh[ei[N_EDGES + e] >> BKT_SHIFT], 1);
    }
    __syncthreads();
    for (int i = threadIdx.x; i < B_BKT; i += 256)
        lbase[i] = lh[i] ? atomicAdd(&bcur16[i * PAD], lh[i]) : 0;
    __syncthreads();
#pragma unroll 4
    for (int k = 0; k < 32; k++) {
        int e = base + k * 256 + threadIdx.x;
        if (e < N_EDGES) {
            int s = ei[e], d = ei[N_EDGES + e];
            int b = d >> BKT_SHIFT;
            int loc = atomicAdd(&lc[b], 1);
            ebuf[lbase[b] + loc] = make_int2(s, d);
        }
    }
}

// S4: per-node in-degree via per-bucket LDS histogram (one block per bucket).
__global__ void __launch_bounds__(256)
k_nhist(const int2* __restrict__ ebuf, const int* __restrict__ boff,
        int* __restrict__ cnt) {
    __shared__ int lcnt[512];
    int b = blockIdx.x;
    int nbase = b << BKT_SHIFT;
    lcnt[threadIdx.x] = 0; lcnt[threadIdx.x + 256] = 0;
    __syncthreads();
    int beg = boff[b], end = boff[b + 1];
    for (int i = beg + threadIdx.x; i < end; i += 256)
        atomicAdd(&lcnt[ebuf[i].y - nbase], 1);
    __syncthreads();
    int n0 = nbase + threadIdx.x, n1 = nbase + 256 + threadIdx.x;
    if (n0 < N_NODES) cnt[n0] = lcnt[threadIdx.x];
    if (n1 < N_NODES) cnt[n1] = lcnt[threadIdx.x + 256];
}

// K3a: per-chunk sums for the hierarchical exclusive scan over nodes.
__global__ void k_scan1(const int* __restrict__ cnt, int* __restrict__ bsum) {
    __shared__ int sh[256];
    int base = blockIdx.x * SCAN_CHUNK;
    int t = threadIdx.x;
    int s = 0;
#pragma unroll
    for (int k = 0; k < 4; k++) {
        int idx = base + t * 4 + k;
        if (idx < N_NODES) s += cnt[idx];
    }
    sh[t] = s; __syncthreads();
    for (int off = 128; off; off >>= 1) {
        if (t < off) sh[t] += sh[t + off];
        __syncthreads();
    }
    if (t == 0) bsum[blockIdx.x] = sh[0];
}

// K3b: exclusive scan of the 196 chunk sums (one block).
__global__ void k_scan2(int* __restrict__ bsum) {
    __shared__ int sh[256];
    int t = threadIdx.x;
    int v = (t < NSCAN_BLOCKS) ? bsum[t] : 0;
    sh[t] = v; __syncthreads();
    for (int off = 1; off < 256; off <<= 1) {
        int add = (t >= off) ? sh[t - off] : 0;
        __syncthreads();
        sh[t] += add;
        __syncthreads();
    }
    if (t < NSCAN_BLOCKS) bsum[t] = sh[t] - v;   // exclusive
}

// K3c: chunk-local scan + chunk offset -> rowptr; norm = rsqrt(deg+1); xp = x*norm.
__global__ void k_scan3(const int* __restrict__ cnt, const int* __restrict__ bsum,
                        int* __restrict__ rowptr, const float* __restrict__ x,
                        float* __restrict__ norm, float* __restrict__ xp) {
    __shared__ int sh[256];
    int base = blockIdx.x * SCAN_CHUNK;
    int t = threadIdx.x;
    int c[4]; int local = 0;
#pragma unroll
    for (int k = 0; k < 4; k++) {
        int idx = base + t * 4 + k;
        c[k] = (idx < N_NODES) ? cnt[idx] : 0;
        local += c[k];
    }
    sh[t] = local; __syncthreads();
    for (int off = 1; off < 256; off <<= 1) {
        int add = (t >= off) ? sh[t - off] : 0;
        __syncthreads();
        sh[t] += add;
        __syncthreads();
    }
    int excl = sh[t] - local + bsum[blockIdx.x];
#pragma unroll
    for (int k = 0; k < 4; k++) {
        int idx = base + t * 4 + k;
        if (idx < N_NODES) {
            rowptr[idx] = excl;
            float nm = rsqrtf((float)c[k] + 1.0f);
            norm[idx] = nm;
            xp[idx] = x[idx] * nm;
            excl += c[k];
        }
    }
    if (blockIdx.x == 0 && t == 0) rowptr[N_NODES] = N_EDGES;
}

// S5: final CSR placement, one block per bucket. Bucket's csrc region (~25 KB)
// is written by a single block -> lines fill in its L2 -> dense writes.
__global__ void __launch_bounds__(256)
k_place(const int2* __restrict__ ebuf, const int* __restrict__ boff,
        const int* __restrict__ rowptr, int* __restrict__ csrc) {
    __shared__ int rb[512], lc[512];
    int b = blockIdx.x;
    int nbase = b << BKT_SHIFT;
#pragma unroll
    for (int k = 0; k < 2; k++) {
        int t = threadIdx.x + k * 256;
        int n = nbase + t;
        rb[t] = (n < N_NODES) ? rowptr[n] : 0;
        lc[t] = 0;
    }
    __syncthreads();
    int beg = boff[b], end = boff[b + 1];
    for (int i = beg + threadIdx.x; i < end; i += 256) {
        int2 e = ebuf[i];
        int li = e.y - nbase;
        int loc = atomicAdd(&lc[li], 1);
        csrc[rb[li] + loc] = e.x;
    }
}

// K5: layer-1 scalar aggregation via gather: s[n] = norm[n]*(xp[n] + sum xp[src]).
__global__ void k_gather1(const int* __restrict__ rowptr, const int* __restrict__ csrc,
                          const float* __restrict__ xp, const float* __restrict__ norm,
                          float* __restrict__ s) {
    int n = blockIdx.x * blockDim.x + threadIdx.x;
    if (n >= N_NODES) return;
    int beg = rowptr[n], end = rowptr[n + 1];
    float acc = xp[n];
    for (int i = beg; i < end; i++) acc += xp[csrc[i]];
    s[n] = norm[n] * acc;
}

// K6: scalar sum / sumsq of s.
__global__ void k_stats_s(const float* __restrict__ s, float* __restrict__ stats) {
    __shared__ float ls[256], lq[256];
    float a = 0.f, q = 0.f;
    for (int i = blockIdx.x * blockDim.x + threadIdx.x; i < N_NODES;
         i += gridDim.x * blockDim.x) {
        float v = s[i];
        a += v; q += v * v;
    }
    ls[threadIdx.x] = a; lq[threadIdx.x] = q;
    __syncthreads();
    for (int off = 128; off; off >>= 1) {
        if (threadIdx.x < (unsigned)off) {
            ls[threadIdx.x] += ls[threadIdx.x + off];
            lq[threadIdx.x] += lq[threadIdx.x + off];
        }
        __syncthreads();
    }
    if (threadIdx.x == 0) { atomAddF(&stats[0], ls[0]); atomAddF(&stats[1], lq[0]); }
}

// K7: fused layer-1 BN+ReLU (rank-1 form) + y1@W2, pre-scaled by norm[n].
__global__ void __launch_bounds__(256)
k_fusedA(const float* __restrict__ s, const float* __restrict__ norm,
         const float* __restrict__ stats, const float* __restrict__ W1,
         const float* __restrict__ g1, const float* __restrict__ be1,
         const float* __restrict__ W2, float* __restrict__ A) {
    __shared__ float w2[32 * 32];
    __shared__ float aj[32], sj[32];
    __shared__ float y[8][33];
    int tid = threadIdx.x;
    for (int i = tid; i < 1024; i += 256) w2[i] = W2[i];
    if (tid < 32) {
        float m   = stats[0] * (1.0f / N_NODES);
        float var = stats[1] * (1.0f / N_NODES) - m * m;
        float w = W1[tid];
        float a = g1[tid] * w * rsqrtf(var * w * w + BN_EPS);
        aj[tid] = a;
        sj[tid] = be1[tid] - m * a;
    }
    int nl = tid >> 5, j = tid & 31;
    int n = blockIdx.x * 8 + nl;
    __syncthreads();
    float sv = (n < N_NODES) ? s[n] : 0.f;
    y[nl][j] = fmaxf(aj[j] * sv + sj[j], 0.f);
    __syncthreads();
    if (n < N_NODES) {
        float acc = 0.f;
#pragma unroll
        for (int k = 0; k < 32; k++) acc += y[nl][k] * w2[k * 32 + j];
        A[n * 32 + j] = acc * norm[n];     // pre-scale by source norm
    }
}

// K8: CSR gather-aggregate for H=32. 8 threads/node, float4 each:
// B[n] = norm[n] * (A[n] + sum_{in-edges} A[src]).
__global__ void __launch_bounds__(256)
k_gather32(const int* __restrict__ rowptr, const int* __restrict__ csrc,
           const float* __restrict__ A, const float* __restrict__ norm,
           float* __restrict__ B) {
    int tid = threadIdx.x;
    int n = blockIdx.x * 32 + (tid >> 3);
    if (n >= N_NODES) return;
    int c = (tid & 7) * 4;
    int beg = rowptr[n], end = rowptr[n + 1];
    float4 acc = *(const float4*)(A + n * 32 + c);    // self-loop term
    int i = beg;
    for (; i + 1 < end; i += 2) {
        int s0 = csrc[i], s1 = csrc[i + 1];
        float4 v0 = *(const float4*)(A + s0 * 32 + c);
        float4 v1 = *(const float4*)(A + s1 * 32 + c);
        acc.x += v0.x + v1.x; acc.y += v0.y + v1.y;
        acc.z += v0.z + v1.z; acc.w += v0.w + v1.w;
    }
    if (i < end) {
        float4 v = *(const float4*)(A + csrc[i] * 32 + c);
        acc.x += v.x; acc.y += v.y; acc.z += v.z; acc.w += v.w;
    }
    float nm = norm[n];
    float4 o; o.x = acc.x * nm; o.y = acc.y * nm; o.z = acc.z * nm; o.w = acc.w * nm;
    *(float4*)(B + n * 32 + c) = o;
}

// K9: per-channel sum/sumsq over the node dimension.
__global__ void k_stats32(const float* __restrict__ agg, float* __restrict__ sum,
                          float* __restrict__ sumsq) {
    int j = threadIdx.x & 31;
    int rl = threadIdx.x >> 5;   // 0..7
    float a = 0.f, q = 0.f;
    for (int n = blockIdx.x * 8 + rl; n < N_NODES; n += gridDim.x * 8) {
        float v = agg[n * 32 + j];
        a += v; q += v * v;
    }
    __shared__ float ls[8][32], lq[8][32];
    ls[rl][j] = a; lq[rl][j] = q;
    __syncthreads();
    for (int off = 4; off; off >>= 1) {
        if (rl < off) { ls[rl][j] += ls[rl + off][j]; lq[rl][j] += lq[rl + off][j]; }
        __syncthreads();
    }
    if (rl == 0) { atomAddF(&sum[j], ls[0][j]); atomAddF(&sumsq[j], lq[0][j]); }
}

// K10: fused BN+ReLU + y@W, pre-scaled by norm[n]. Reads B, writes A.
__global__ void __launch_bounds__(256)
k_fusedB(const float* __restrict__ norm, const float* __restrict__ sum,
         const float* __restrict__ sumsq, const float* __restrict__ g,
         const float* __restrict__ be, const float* __restrict__ W,
         const float* __restrict__ aggIn, float* __restrict__ hOut) {
    __shared__ float wl[1024];
    __shared__ float sc[32], sh[32];
    __shared__ float y[8][33];
    int tid = threadIdx.x;
    for (int i = tid; i < 1024; i += 256) wl[i] = W[i];
    if (tid < 32) {
        float m   = sum[tid] * (1.0f / N_NODES);
        float var = sumsq[tid] * (1.0f / N_NODES) - m * m;
        float scj = g[tid] * rsqrtf(var + BN_EPS);
        sc[tid] = scj;
        sh[tid] = be[tid] - m * scj;
    }
    int nl = tid >> 5, j = tid & 31;
    int n = blockIdx.x * 8 + nl;
    __syncthreads();
    float yv = 0.f;
    if (n < N_NODES) yv = fmaxf(sc[j] * aggIn[n * 32 + j] + sh[j], 0.f);
    y[nl][j] = yv;
    __syncthreads();
    if (n < N_NODES) {
        float acc = 0.f;
#pragma unroll
        for (int k = 0; k < 32; k++) acc += y[nl][k] * wl[k * 32 + j];
        hOut[n * 32 + j] = acc * norm[n];
    }
}

// K11: final BN+ReLU + dot with fcW + fcb.
__global__ void __launch_bounds__(256)
k_final(const float* __restrict__ aggIn, const float* __restrict__ sum,
        const float* __restrict__ sumsq, const float* __restrict__ g,
        const float* __restrict__ be, const float* __restrict__ fcW,
        const float* __restrict__ fcb, float* __restrict__ out) {
    __shared__ float sc[32], sh[32], fw[32];
    int tid = threadIdx.x;
    if (tid < 32) {
        float m   = sum[tid] * (1.0f / N_NODES);
        float var = sumsq[tid] * (1.0f / N_NODES) - m * m;
        float scj = g[tid] * rsqrtf(var + BN_EPS);
        sc[tid] = scj;
        sh[tid] = be[tid] - m * scj;
        fw[tid] = fcW[tid];
    }
    __syncthreads();
    int nl = tid >> 5, j = tid & 31;
    int n = blockIdx.x * 8 + nl;
    float v = 0.f;
    if (n < N_NODES) v = fmaxf(sc[j] * aggIn[n * 32 + j] + sh[j], 0.f) * fw[j];
    for (int off = 16; off; off >>= 1) v += __shfl_down(v, off, 32);
    if (j == 0 && n < N_NODES) out[n] = v + fcb[0];
}

extern "C" void kernel_launch(void* const* d_in, const int* in_sizes, int n_in,
                              void* d_out, int out_size, void* d_ws, size_t ws_size,
                              hipStream_t stream) {
    const float* x   = (const float*)d_in[0];
    const int*   ei  = (const int*)d_in[1];
    // d_in[2] edge_attr: unused by the reference
    const float* W1  = (const float*)d_in[3];
    // b1/b2/b3 cancel under training-mode BN
    const float* g1  = (const float*)d_in[5];
    const float* be1 = (const float*)d_in[6];
    const float* W2  = (const float*)d_in[7];
    const float* g2  = (const float*)d_in[9];
    const float* be2 = (const float*)d_in[10];
    const float* W3  = (const float*)d_in[11];
    const float* g3  = (const float*)d_in[13];
    const float* be3 = (const float*)d_in[14];
    const float* fcW = (const float*)d_in[15];
    const float* fcb = (const float*)d_in[16];
    float* out = (float*)d_out;

    // Workspace layout. ebuf (int2[E] = 20 MB) OVERLAYS A (25.6 MB): ebuf's
    // last reader (k_place) runs strictly before A's first writer (k_fusedA).
    float* A      = (float*)d_ws;                   // [N*32]
    int2*  ebuf   = (int2*)d_ws;                    // [E]  (overlay)
    float* B      = A + N_NODES * 32;               // [N*32]
    int*   csrc   = (int*)(B + N_NODES * 32);       // [E]
    int*   cnt    = csrc + N_EDGES;                 // [N]
    int*   rowptr = cnt + N_NODES;                  // [N+1]
    int*   bsum   = rowptr + N_NODES + 1;           // [256]
    int*   bcnt16 = bsum + 256;                     // [B_BKT*16]
    int*   bcur16 = bcnt16 + B_BKT * PAD;           // [B_BKT*16]
    int*   boff   = bcur16 + B_BKT * PAD;           // [B_BKT+1]
    float* norm   = (float*)(boff + B_BKT + 1);     // [N]
    float* xp     = norm + N_NODES;                 // [N]
    float* s      = xp + N_NODES;                   // [N]
    float* stats  = s + N_NODES;                    // [256]

    const int nbN = (N_NODES + 255) / 256;
    const int nbZ = (B_BKT * PAD + 255) / 256;
    const int nbNode8  = (N_NODES + 7) / 8;
    const int nbNode32 = (N_NODES + 31) / 32;

    k_init    <<<nbZ, 256, 0, stream>>>(bcnt16, stats);
    k_bhist   <<<NB_SCAT, 256, 0, stream>>>(ei, bcnt16);
    k_bscan   <<<1, 256, 0, stream>>>(bcnt16, boff, bcur16);
    k_scatterB<<<NB_SCAT, 256, 0, stream>>>(ei, bcur16, ebuf);
    k_nhist   <<<B_BKT, 256, 0, stream>>>(ebuf, boff, cnt);
    k_scan1   <<<NSCAN_BLOCKS, 256, 0, stream>>>(cnt, bsum);
    k_scan2   <<<1, 256, 0, stream>>>(bsum);
    k_scan3   <<<NSCAN_BLOCKS, 256, 0, stream>>>(cnt, bsum, rowptr, x, norm, xp);
    k_place   <<<B_BKT, 256, 0, stream>>>(ebuf, boff, rowptr, csrc);
    k_gather1 <<<nbN, 256, 0, stream>>>(rowptr, csrc, xp, norm, s);
    k_stats_s <<<256, 256, 0, stream>>>(s, stats);
    k_fusedA  <<<nbNode8, 256, 0, stream>>>(s, norm, stats, W1, g1, be1, W2, A);
    k_gather32<<<nbNode32, 256, 0, stream>>>(rowptr, csrc, A, norm, B);
    k_stats32 <<<512, 256, 0, stream>>>(B, stats + 8, stats + 40);
    k_fusedB  <<<nbNode8, 256, 0, stream>>>(norm, stats + 8, stats + 40, g2, be2, W3, B, A);
    k_gather32<<<nbNode32, 256, 0, stream>>>(rowptr, csrc, A, norm, B);
    k_stats32 <<<512, 256, 0, stream>>>(B, stats + 72, stats + 104);
    k_final   <<<nbNode8, 256, 0, stream>>>(B, stats + 72, stats + 104, g3, be3, fcW, fcb, out);
}

// Round 4
// 451.552 us; speedup vs baseline: 5.5652x; 1.0267x over previous
//
#include <hip/hip_runtime.h>
#include <hip/hip_bf16.h>
#include <hip/hip_fp16.h>

#define N_NODES 200000
#define N_EDGES 2500000
#define HID 32
#define BN_EPS 1e-5f

#define BKT_SHIFT 9                      // 512 nodes per bucket
#define B_BKT ((N_NODES + 511) / 512)    // 391 buckets
#define PAD 16                           // one counter per 64B line
#define CAPB 7680                        // bucket capacity (mean 6394 + 16 sigma)
#define EDGES_PER_BLK 2048
#define NB_SCAT ((N_EDGES + EDGES_PER_BLK - 1) / EDGES_PER_BLK)  // 1221

__device__ __forceinline__ void atomAddF(float* p, float v) {
    unsafeAtomicAdd(p, v);   // native global_atomic_add_f32 on gfx950
}

// K0: zero bucket cursors + stats scratch.
__global__ void k_init(int* __restrict__ bcur16, float* __restrict__ stats) {
    int i = blockIdx.x * blockDim.x + threadIdx.x;
    if (i < B_BKT * PAD) bcur16[i] = 0;
    if (i < 256) stats[i] = 0.0f;
}

// S1: scatter edges into capacity-padded buckets (grouped by dst>>9).
// Per-block LDS histogram -> one global reservation per (block,bucket) keeps
// each block's writes contiguous per bucket.
__global__ void __launch_bounds__(256)
k_scatter(const int* __restrict__ ei, int* __restrict__ bcur16,
          int2* __restrict__ ebuf) {
    __shared__ int lh[B_BKT], lbase[B_BKT], lc[B_BKT];
    for (int i = threadIdx.x; i < B_BKT; i += 256) { lh[i] = 0; lc[i] = 0; }
    __syncthreads();
    int base = blockIdx.x * EDGES_PER_BLK;
#pragma unroll
    for (int k = 0; k < EDGES_PER_BLK / 256; k++) {
        int e = base + k * 256 + threadIdx.x;
        if (e < N_EDGES) atomicAdd(&lh[ei[N_EDGES + e] >> BKT_SHIFT], 1);
    }
    __syncthreads();
    for (int i = threadIdx.x; i < B_BKT; i += 256)
        lbase[i] = lh[i] ? atomicAdd(&bcur16[i * PAD], lh[i]) : 0;
    __syncthreads();
#pragma unroll
    for (int k = 0; k < EDGES_PER_BLK / 256; k++) {
        int e = base + k * 256 + threadIdx.x;
        if (e < N_EDGES) {
            int s = ei[e], d = ei[N_EDGES + e];
            int b = d >> BKT_SHIFT;
            int loc = atomicAdd(&lc[b], 1);
            ebuf[(size_t)b * CAPB + lbase[b] + loc] = make_int2(s, d & 511);
        }
    }
}

// S2: one block per bucket. Fuses: per-node degree histogram, local exclusive
// scan (-> capacity-padded CSR row bases), norm = rsqrt(deg+1), xp = x*norm,
// and CSR placement. Bucket's csrc region is single-writer -> dense lines.
__global__ void __launch_bounds__(256)
k_bucket(const int2* __restrict__ ebuf, const int* __restrict__ bcur16,
         const float* __restrict__ x, int* __restrict__ rowbeg,
         int* __restrict__ cntg, float* __restrict__ norm,
         float* __restrict__ xp, int* __restrict__ csrc) {
    __shared__ int hist[512], sh[512], rbase[512];
    int b = blockIdx.x;
    int t = threadIdx.x;
    int count = bcur16[b * PAD];
    size_t ebase = (size_t)b * CAPB;
    int nbase = b << BKT_SHIFT;
    hist[t] = 0; hist[t + 256] = 0;
    __syncthreads();
    for (int i = t; i < count; i += 256) atomicAdd(&hist[ebuf[ebase + i].y], 1);
    __syncthreads();
    // Hillis-Steele inclusive scan over 512 entries (2 per thread).
    int v0 = hist[t], v1 = hist[t + 256];
    sh[t] = v0; sh[t + 256] = v1;
    __syncthreads();
    for (int off = 1; off < 512; off <<= 1) {
        int a = (t >= off) ? sh[t - off] : 0;
        int c = (t + 256 >= off) ? sh[t + 256 - off] : 0;
        __syncthreads();
        sh[t] += a; sh[t + 256] += c;
        __syncthreads();
    }
#pragma unroll
    for (int k = 0; k < 2; k++) {
        int tt = t + k * 256;
        int vv = k ? v1 : v0;
        int excl = sh[tt] - vv;
        int rb = (int)ebase + excl;
        rbase[tt] = rb;
        int n = nbase + tt;
        if (n < N_NODES) {
            rowbeg[n] = rb;
            cntg[n] = vv;
            float nm = rsqrtf((float)vv + 1.0f);
            norm[n] = nm;
            xp[n] = x[n] * nm;
        }
    }
    __syncthreads();
    hist[t] = 0; hist[t + 256] = 0;   // reuse as placement cursors
    __syncthreads();
    for (int i = t; i < count; i += 256) {
        int2 e = ebuf[ebase + i];
        int loc = atomicAdd(&hist[e.y], 1);
        csrc[rbase[e.y] + loc] = e.x;
    }
}

// K5: layer-1 scalar gather: s[n] = norm[n]*(xp[n] + sum xp[src]).
__global__ void k_gather1(const int* __restrict__ rowbeg, const int* __restrict__ cntg,
                          const int* __restrict__ csrc, const float* __restrict__ xp,
                          const float* __restrict__ norm, float* __restrict__ s) {
    int n = blockIdx.x * blockDim.x + threadIdx.x;
    if (n >= N_NODES) return;
    int beg = rowbeg[n], dg = cntg[n];
    float acc = xp[n];
    for (int i = 0; i < dg; i++) acc += xp[csrc[beg + i]];
    s[n] = norm[n] * acc;
}

// K6: scalar sum / sumsq of s.
__global__ void k_stats_s(const float* __restrict__ s, float* __restrict__ stats) {
    __shared__ float ls[256], lq[256];
    float a = 0.f, q = 0.f;
    for (int i = blockIdx.x * blockDim.x + threadIdx.x; i < N_NODES;
         i += gridDim.x * blockDim.x) {
        float v = s[i];
        a += v; q += v * v;
    }
    ls[threadIdx.x] = a; lq[threadIdx.x] = q;
    __syncthreads();
    for (int off = 128; off; off >>= 1) {
        if (threadIdx.x < (unsigned)off) {
            ls[threadIdx.x] += ls[threadIdx.x + off];
            lq[threadIdx.x] += lq[threadIdx.x + off];
        }
        __syncthreads();
    }
    if (threadIdx.x == 0) { atomAddF(&stats[0], ls[0]); atomAddF(&stats[1], lq[0]); }
}

// K7: fused layer-1 BN+ReLU (rank-1 form) + y1@W2, pre-scaled by norm[n].
// Writes A in f16 (halves gather traffic).
__global__ void __launch_bounds__(256)
k_fusedA(const float* __restrict__ s, const float* __restrict__ norm,
         const float* __restrict__ stats, const float* __restrict__ W1,
         const float* __restrict__ g1, const float* __restrict__ be1,
         const float* __restrict__ W2, __half* __restrict__ A) {
    __shared__ float w2[32 * 32];
    __shared__ float aj[32], sj[32];
    __shared__ float y[8][33];
    int tid = threadIdx.x;
    for (int i = tid; i < 1024; i += 256) w2[i] = W2[i];
    if (tid < 32) {
        float m   = stats[0] * (1.0f / N_NODES);
        float var = stats[1] * (1.0f / N_NODES) - m * m;
        float w = W1[tid];
        float a = g1[tid] * w * rsqrtf(var * w * w + BN_EPS);
        aj[tid] = a;
        sj[tid] = be1[tid] - m * a;
    }
    int nl = tid >> 5, j = tid & 31;
    int n = blockIdx.x * 8 + nl;
    __syncthreads();
    float sv = (n < N_NODES) ? s[n] : 0.f;
    y[nl][j] = fmaxf(aj[j] * sv + sj[j], 0.f);
    __syncthreads();
    if (n < N_NODES) {
        float acc = 0.f;
#pragma unroll
        for (int k = 0; k < 32; k++) acc += y[nl][k] * w2[k * 32 + j];
        A[n * 32 + j] = __float2half(acc * norm[n]);
    }
}

__device__ __forceinline__ void load8h(const __half* p, float2& f0, float2& f1,
                                       float2& f2, float2& f3) {
    const __half2* h = (const __half2*)p;   // 16B-aligned
    f0 = __half22float2(h[0]);
    f1 = __half22float2(h[1]);
    f2 = __half22float2(h[2]);
    f3 = __half22float2(h[3]);
}

// K8: CSR gather-aggregate, f16 messages. 4 threads/node, 8 channels each:
// B[n] = norm[n] * (A[n] + sum_{in-edges} A[src]).   (B stays fp32.)
__global__ void __launch_bounds__(256)
k_gather32(const int* __restrict__ rowbeg, const int* __restrict__ cntg,
           const int* __restrict__ csrc, const __half* __restrict__ A,
           const float* __restrict__ norm, float* __restrict__ B) {
    int tid = threadIdx.x;
    int n = blockIdx.x * 64 + (tid >> 2);
    if (n >= N_NODES) return;
    int c8 = (tid & 3) * 8;
    int beg = rowbeg[n], dg = cntg[n];
    float2 a0, a1, a2, a3;
    load8h(A + n * 32 + c8, a0, a1, a2, a3);   // self-loop term
    int i = 0;
    for (; i + 1 < dg; i += 2) {
        int s0 = csrc[beg + i], s1 = csrc[beg + i + 1];
        float2 b0, b1, b2, b3, c0, c1, c2, c3;
        load8h(A + s0 * 32 + c8, b0, b1, b2, b3);
        load8h(A + s1 * 32 + c8, c0, c1, c2, c3);
        a0.x += b0.x + c0.x; a0.y += b0.y + c0.y;
        a1.x += b1.x + c1.x; a1.y += b1.y + c1.y;
        a2.x += b2.x + c2.x; a2.y += b2.y + c2.y;
        a3.x += b3.x + c3.x; a3.y += b3.y + c3.y;
    }
    if (i < dg) {
        float2 b0, b1, b2, b3;
        load8h(A + csrc[beg + i] * 32 + c8, b0, b1, b2, b3);
        a0.x += b0.x; a0.y += b0.y; a1.x += b1.x; a1.y += b1.y;
        a2.x += b2.x; a2.y += b2.y; a3.x += b3.x; a3.y += b3.y;
    }
    float nm = norm[n];
    float4 o0 = make_float4(a0.x * nm, a0.y * nm, a1.x * nm, a1.y * nm);
    float4 o1 = make_float4(a2.x * nm, a2.y * nm, a3.x * nm, a3.y * nm);
    *(float4*)(B + n * 32 + c8) = o0;
    *(float4*)(B + n * 32 + c8 + 4) = o1;
}

// K9: per-channel sum/sumsq over the node dimension.
__global__ void k_stats32(const float* __restrict__ agg, float* __restrict__ sum,
                          float* __restrict__ sumsq) {
    int j = threadIdx.x & 31;
    int rl = threadIdx.x >> 5;   // 0..7
    float a = 0.f, q = 0.f;
    for (int n = blockIdx.x * 8 + rl; n < N_NODES; n += gridDim.x * 8) {
        float v = agg[n * 32 + j];
        a += v; q += v * v;
    }
    __shared__ float ls[8][32], lq[8][32];
    ls[rl][j] = a; lq[rl][j] = q;
    __syncthreads();
    for (int off = 4; off; off >>= 1) {
        if (rl < off) { ls[rl][j] += ls[rl + off][j]; lq[rl][j] += lq[rl + off][j]; }
        __syncthreads();
    }
    if (rl == 0) { atomAddF(&sum[j], ls[0][j]); atomAddF(&sumsq[j], lq[0][j]); }
}

// K10: fused BN+ReLU + y@W, pre-scaled by norm[n]. Reads B fp32, writes A f16.
__global__ void __launch_bounds__(256)
k_fusedB(const float* __restrict__ norm, const float* __restrict__ sum,
         const float* __restrict__ sumsq, const float* __restrict__ g,
         const float* __restrict__ be, const float* __restrict__ W,
         const float* __restrict__ aggIn, __half* __restrict__ hOut) {
    __shared__ float wl[1024];
    __shared__ float sc[32], sh[32];
    __shared__ float y[8][33];
    int tid = threadIdx.x;
    for (int i = tid; i < 1024; i += 256) wl[i] = W[i];
    if (tid < 32) {
        float m   = sum[tid] * (1.0f / N_NODES);
        float var = sumsq[tid] * (1.0f / N_NODES) - m * m;
        float scj = g[tid] * rsqrtf(var + BN_EPS);
        sc[tid] = scj;
        sh[tid] = be[tid] - m * scj;
    }
    int nl = tid >> 5, j = tid & 31;
    int n = blockIdx.x * 8 + nl;
    __syncthreads();
    float yv = 0.f;
    if (n < N_NODES) yv = fmaxf(sc[j] * aggIn[n * 32 + j] + sh[j], 0.f);
    y[nl][j] = yv;
    __syncthreads();
    if (n < N_NODES) {
        float acc = 0.f;
#pragma unroll
        for (int k = 0; k < 32; k++) acc += y[nl][k] * wl[k * 32 + j];
        hOut[n * 32 + j] = __float2half(acc * norm[n]);
    }
}

// K11: final BN+ReLU + dot with fcW + fcb.
__global__ void __launch_bounds__(256)
k_final(const float* __restrict__ aggIn, const float* __restrict__ sum,
        const float* __restrict__ sumsq, const float* __restrict__ g,
        const float* __restrict__ be, const float* __restrict__ fcW,
        const float* __restrict__ fcb, float* __restrict__ out) {
    __shared__ float sc[32], sh[32], fw[32];
    int tid = threadIdx.x;
    if (tid < 32) {
        float m   = sum[tid] * (1.0f / N_NODES);
        float var = sumsq[tid] * (1.0f / N_NODES) - m * m;
        float scj = g[tid] * rsqrtf(var + BN_EPS);
        sc[tid] = scj;
        sh[tid] = be[tid] - m * scj;
        fw[tid] = fcW[tid];
    }
    __syncthreads();
    int nl = tid >> 5, j = tid & 31;
    int n = blockIdx.x * 8 + nl;
    float v = 0.f;
    if (n < N_NODES) v = fmaxf(sc[j] * aggIn[n * 32 + j] + sh[j], 0.f) * fw[j];
    for (int off = 16; off; off >>= 1) v += __shfl_down(v, off, 32);
    if (j == 0 && n < N_NODES) out[n] = v + fcb[0];
}

extern "C" void kernel_launch(void* const* d_in, const int* in_sizes, int n_in,
                              void* d_out, int out_size, void* d_ws, size_t ws_size,
                              hipStream_t stream) {
    const float* x   = (const float*)d_in[0];
    const int*   ei  = (const int*)d_in[1];
    // d_in[2] edge_attr: unused by the reference
    const float* W1  = (const float*)d_in[3];
    // b1/b2/b3 cancel under training-mode BN
    const float* g1  = (const float*)d_in[5];
    const float* be1 = (const float*)d_in[6];
    const float* W2  = (const float*)d_in[7];
    const float* g2  = (const float*)d_in[9];
    const float* be2 = (const float*)d_in[10];
    const float* W3  = (const float*)d_in[11];
    const float* g3  = (const float*)d_in[13];
    const float* be3 = (const float*)d_in[14];
    const float* fcW = (const float*)d_in[15];
    const float* fcb = (const float*)d_in[16];
    float* out = (float*)d_out;

    // Workspace layout (bytes):
    //   [0, 12.8M)          A   (__half, N*32)          \  overlaid by ebuf
    //   [12.8M, 38.4M)      B   (float, N*32)           /  (first 24.0M)
    //   ebuf = int2[B_BKT*CAPB] = 24.0MB at offset 0 — last read (k_bucket)
    //   strictly precedes first writes of A (k_fusedA) and B (k_gather32).
    //   [38.4M, ...)        csrc, rowbeg, cntg, norm, xp, s, stats, bcur16
    char* base = (char*)d_ws;
    __half* A      = (__half*)base;                       // N*32 f16
    float*  B      = (float*)(base + (size_t)N_NODES * 32 * 2);
    int2*   ebuf   = (int2*)base;                         // overlay
    int*    csrc   = (int*)(base + (size_t)N_NODES * 32 * 2 + (size_t)N_NODES * 32 * 4);
    int*    rowbeg = csrc + (size_t)B_BKT * CAPB;
    int*    cntg   = rowbeg + N_NODES;
    float*  norm   = (float*)(cntg + N_NODES);
    float*  xp     = norm + N_NODES;
    float*  s      = xp + N_NODES;
    float*  stats  = s + N_NODES;                         // [256]
    int*    bcur16 = (int*)(stats + 256);                 // [B_BKT*16]

    const int nbN = (N_NODES + 255) / 256;
    const int nbZ = (B_BKT * PAD + 255) / 256;
    const int nbNode8  = (N_NODES + 7) / 8;
    const int nbNode64 = (N_NODES + 63) / 64;

    k_init    <<<nbZ, 256, 0, stream>>>(bcur16, stats);
    k_scatter <<<NB_SCAT, 256, 0, stream>>>(ei, bcur16, ebuf);
    k_bucket  <<<B_BKT, 256, 0, stream>>>(ebuf, bcur16, x, rowbeg, cntg, norm, xp, csrc);
    k_gather1 <<<nbN, 256, 0, stream>>>(rowbeg, cntg, csrc, xp, norm, s);
    k_stats_s <<<256, 256, 0, stream>>>(s, stats);
    k_fusedA  <<<nbNode8, 256, 0, stream>>>(s, norm, stats, W1, g1, be1, W2, A);
    k_gather32<<<nbNode64, 256, 0, stream>>>(rowbeg, cntg, csrc, A, norm, B);
    k_stats32 <<<512, 256, 0, stream>>>(B, stats + 8, stats + 40);
    k_fusedB  <<<nbNode8, 256, 0, stream>>>(norm, stats + 8, stats + 40, g2, be2, W3, B, A);
    k_gather32<<<nbNode64, 256, 0, stream>>>(rowbeg, cntg, csrc, A, norm, B);
    k_stats32 <<<512, 256, 0, stream>>>(B, stats + 72, stats + 104);
    k_final   <<<nbNode8, 256, 0, stream>>>(B, stats + 72, stats + 104, g3, be3, fcW, fcb, out);
}